// Round 5
// baseline (521.098 us; speedup 1.0000x reference)
//
#include <hip/hip_runtime.h>
#include <math.h>

#define NPG 256
#define NB 1024
#define NN (NB * NPG)          // 262144 nodes
#define HID 192
#define HID2 384
#define NE 4194304
#define KTOP 231
#define LNEPS 1e-5f

#define BM 32                  // rows per block (logits kernel) — small tile
                               // so LDS=24.5KB -> 5 blocks/CU (pool ~128KB)

typedef short short8 __attribute__((ext_vector_type(8)));
typedef float f32x4  __attribute__((ext_vector_type(4)));

// fp32 -> bf16 (RNE) and back, bit-exact helpers
__device__ __forceinline__ short f2bf(float f) {
    unsigned u = __float_as_uint(f);
    u += 0x7fffu + ((u >> 16) & 1u);
    return (short)(u >> 16);
}
__device__ __forceinline__ float bf2f(short h) {
    return __uint_as_float(((unsigned)(unsigned short)h) << 16);
}

__device__ __forceinline__ void dec8(float4 a, float4 b, short8& hv, short8& lv) {
#define DEC1(i, val) { short h_ = f2bf(val); hv[i] = h_; lv[i] = f2bf((val) - bf2f(h_)); }
    DEC1(0, a.x) DEC1(1, a.y) DEC1(2, a.z) DEC1(3, a.w)
    DEC1(4, b.x) DEC1(5, b.y) DEC1(6, b.z) DEC1(7, b.w)
#undef DEC1
}

// ---------------------------------------------------------------------------
// Kernel W: pack W1 [192][384] fp32 into MFMA B-fragment order, bf16 hi/lo.
// Layout: [slice s:6][frag f:24][comp c:2][lane:64][e:8] halves.
// Fragment element: W1[s*32 + 8*(lane>>4) + e][f*16 + (lane&15)].
// ---------------------------------------------------------------------------
__global__ __launch_bounds__(256) void wpack_kernel(
    const float* __restrict__ W1, short* __restrict__ W1P)
{
    const int t    = blockIdx.x * 256 + threadIdx.x;   // 0..18431
    const int lane = t & 63;
    const int c    = (t >> 6) & 1;
    const int fs   = t >> 7;
    const int f    = fs % 24;
    const int s    = fs / 24;
    const int col  = f * 16 + (lane & 15);
    const int kb   = s * 32 + 8 * (lane >> 4);
    short8 o;
#define PK(e) { float w = W1[(size_t)(kb + e) * HID2 + col]; \
                short hi = f2bf(w); \
                o[e] = (c == 0) ? hi : f2bf(w - bf2f(hi)); }
    PK(0) PK(1) PK(2) PK(3) PK(4) PK(5) PK(6) PK(7)
#undef PK
    ((short8*)W1P)[t] = o;
}

// ---------------------------------------------------------------------------
// Kernel A: fused logits via bf16x3 emulated-fp32 MFMA GEMM (hh + hl + lh;
// ll term <= 2^-18 relative, dropped). Block = 32 rows x 384 cols, 4 waves
// each own 32 rows x 96 cols (2 M-frags x 6 N-frags of 16x16). K = 6x32.
// Occupancy fix (this round): BM 64->32 cuts LDS to 24576 B => 5 blocks/CU
// (~20 waves) so B-load / ds_read latency is TLP-hidden. K-loop is the
// compiler-scheduled R3 form (explicit dist-2 pipeline regressed, R4).
// ---------------------------------------------------------------------------
union SMemU {
    struct { short Xh[BM * HID]; short Xl[BM * HID]; } x;             // 24576 B
    struct { float2 red[BM][4]; float2 mrs[BM]; float pl[BM][4]; } e; // 1792 B
};

__global__ __launch_bounds__(256) void logits_kernel(
    const float* __restrict__ h, const float* __restrict__ g,
    const short* __restrict__ W1P, const float* __restrict__ b1,
    const float* __restrict__ gamma, const float* __restrict__ beta,
    const float* __restrict__ W2, const float* __restrict__ b2,
    float* __restrict__ logits_out)
{
    __shared__ __align__(16) SMemU sm;

    const int tid   = threadIdx.x;
    const int lane  = tid & 63;
    const int wv    = tid >> 6;        // 0..3 : column quarter
    const int li    = lane & 15;
    const int gq    = lane >> 4;       // 0..3 : k-group
    const int row0  = blockIdx.x * BM;
    const int graph = row0 >> 8;

    // ---- stage X = h + g_rep, decomposed to bf16 hi/lo, swizzled ----
    {
        const float4* h4 = (const float4*)(h + (size_t)row0 * HID);
        const float4* g4 = (const float4*)(g + (size_t)graph * HID);
        #pragma unroll
        for (int it = 0; it < 3; ++it) {
            int fidx = tid + it * 256;           // 0..767
            int row  = fidx / 24;
            int k8   = fidx - row * 24;          // 8-elem group within row
            float4 a  = h4[row * 48 + k8 * 2];
            float4 b  = h4[row * 48 + k8 * 2 + 1];
            float4 ga = g4[k8 * 2];
            float4 gb = g4[k8 * 2 + 1];
            a.x += ga.x; a.y += ga.y; a.z += ga.z; a.w += ga.w;
            b.x += gb.x; b.y += gb.y; b.z += gb.z; b.w += gb.w;
            short8 hv, lv;
            dec8(a, b, hv, lv);
            int idx = row * HID + ((k8 ^ (row & 7)) << 3);   // 16B-granule swizzle
            *(short8*)(sm.x.Xh + idx) = hv;
            *(short8*)(sm.x.Xl + idx) = lv;
        }
    }
    __syncthreads();

    f32x4 acc[2][6];
    #pragma unroll
    for (int m = 0; m < 2; ++m)
        #pragma unroll
        for (int n = 0; n < 6; ++n)
            acc[m][n] = (f32x4){0.f, 0.f, 0.f, 0.f};

    const short8* wp = (const short8*)W1P;
    const int bbase = wv * 768 + lane;   // (wv*6 frags)*2 comp*64 lanes

    #pragma unroll
    for (int s = 0; s < 6; ++s) {
        // B fragments for this K-slice (coalesced 1KB loads, L2-resident)
        short8 Bh[6], Bl[6];
        #pragma unroll
        for (int n = 0; n < 6; ++n) {
            Bh[n] = wp[s * 3072 + bbase + n * 128];
            Bl[n] = wp[s * 3072 + bbase + n * 128 + 64];
        }
        // A fragments from swizzled LDS
        short8 Ah[2], Al[2];
        #pragma unroll
        for (int m = 0; m < 2; ++m) {
            int row = m * 16 + li;
            int idx = row * HID + ((((s << 2) + gq) ^ (li & 7)) << 3);
            Ah[m] = *(const short8*)(sm.x.Xh + idx);
            Al[m] = *(const short8*)(sm.x.Xl + idx);
        }
        // bf16x3: hh + hl + lh (ll dropped, <= 2^-18 rel)
        #pragma unroll
        for (int m = 0; m < 2; ++m)
            #pragma unroll
            for (int n = 0; n < 6; ++n) {
                acc[m][n] = __builtin_amdgcn_mfma_f32_16x16x32_bf16(Ah[m], Bh[n], acc[m][n], 0, 0, 0);
                acc[m][n] = __builtin_amdgcn_mfma_f32_16x16x32_bf16(Ah[m], Bl[n], acc[m][n], 0, 0, 0);
                acc[m][n] = __builtin_amdgcn_mfma_f32_16x16x32_bf16(Al[m], Bh[n], acc[m][n], 0, 0, 0);
            }
    }
    __syncthreads();   // Xh/Xl dead from here; epilogue scratch aliases them

    // ---- epilogue: +b1, LayerNorm, ReLU, dot W2 ----
    // C/D layout: col = n*16 + li (wave offset wv*96), row = m*16 + gq*4 + r
    float b1v[6], gav[6], bev[6], w2v[6];
    #pragma unroll
    for (int n = 0; n < 6; ++n) {
        int c = wv * 96 + n * 16 + li;
        b1v[n] = b1[c]; gav[n] = gamma[c]; bev[n] = beta[c]; w2v[n] = W2[c];
    }

    #pragma unroll
    for (int m = 0; m < 2; ++m) {
        #pragma unroll
        for (int r = 0; r < 4; ++r) {
            float s1 = 0.f, s2 = 0.f;
            #pragma unroll
            for (int n = 0; n < 6; ++n) {
                float z = acc[m][n][r] + b1v[n];
                s1 += z;
                s2 = fmaf(z, z, s2);
            }
            #pragma unroll
            for (int off = 1; off < 16; off <<= 1) {
                s1 += __shfl_xor(s1, off);
                s2 += __shfl_xor(s2, off);
            }
            if (li == 0) {
                int row = m * 16 + gq * 4 + r;
                sm.e.red[row][wv] = make_float2(s1, s2);
            }
        }
    }
    __syncthreads();
    if (tid < BM) {
        float2 p0 = sm.e.red[tid][0], p1 = sm.e.red[tid][1];
        float2 p2 = sm.e.red[tid][2], p3 = sm.e.red[tid][3];
        float s1 = (p0.x + p1.x) + (p2.x + p3.x);
        float s2 = (p0.y + p1.y) + (p2.y + p3.y);
        float mu  = s1 * (1.f / HID2);
        float var = s2 * (1.f / HID2) - mu * mu;
        sm.e.mrs[tid] = make_float2(mu, rsqrtf(var + LNEPS));
    }
    __syncthreads();

    #pragma unroll
    for (int m = 0; m < 2; ++m) {
        #pragma unroll
        for (int r = 0; r < 4; ++r) {
            int row = m * 16 + gq * 4 + r;
            float2 v = sm.e.mrs[row];
            float p = 0.f;
            #pragma unroll
            for (int n = 0; n < 6; ++n) {
                float z  = acc[m][n][r] + b1v[n];
                float zn = (z - v.x) * v.y * gav[n] + bev[n];
                p = fmaf(fmaxf(zn, 0.f), w2v[n], p);
            }
            #pragma unroll
            for (int off = 1; off < 16; off <<= 1) p += __shfl_xor(p, off);
            if (li == 0) sm.e.pl[row][wv] = p;
        }
    }
    __syncthreads();
    if (tid < BM) {
        float lg = (sm.e.pl[tid][0] + sm.e.pl[tid][1]) + (sm.e.pl[tid][2] + sm.e.pl[tid][3]);
        logits_out[row0 + tid] = lg + b2[0];
    }
}

// ---------------------------------------------------------------------------
// Kernel B: per-graph top-K via rank counting (stable, ties by lower index =
// jax.lax.top_k). Emits kl[n] = kept ? logit : NaN (single 4B gather later).
// Also zeroes touched bytes.
// ---------------------------------------------------------------------------
__global__ __launch_bounds__(256) void topk_kernel(
    const float* __restrict__ logits, float* __restrict__ kl,
    unsigned char* __restrict__ touched)
{
    __shared__ float arr[NPG];
    const int tid = threadIdx.x;
    const int n = blockIdx.x * NPG + tid;
    float v = logits[n];
    arr[tid] = v;
    touched[n] = 0;
    __syncthreads();
    int rank = 0;
    #pragma unroll 16
    for (int j = 0; j < NPG; ++j) {
        float a = arr[j];
        rank += (a > v || (a == v && j < tid)) ? 1 : 0;
    }
    kl[n] = (rank < KTOP) ? v : __builtin_nanf("");
}

// ---------------------------------------------------------------------------
// Kernel C: edge mask + weight + touched marking. NaN-poisoned logits make
// mask = !isnan(ls+ld). Plain idempotent uchar stores to touched.
// ---------------------------------------------------------------------------
__global__ __launch_bounds__(256) void edge_kernel(
    const int* __restrict__ ei, const float* __restrict__ kl,
    float4* __restrict__ mask_out, float4* __restrict__ w_out,
    unsigned char* __restrict__ touched)
{
    const int t = blockIdx.x * blockDim.x + threadIdx.x;   // [0, NE/4)
    const int4 s4 = ((const int4*)ei)[t];
    const int4 d4 = ((const int4*)(ei + NE))[t];

    float m[4], w[4];
    const int ss[4] = {s4.x, s4.y, s4.z, s4.w};
    const int dd[4] = {d4.x, d4.y, d4.z, d4.w};
    #pragma unroll
    for (int i = 0; i < 4; ++i) {
        float ls = kl[ss[i]];
        float ld = kl[dd[i]];
        float sum = ls + ld;
        bool ok = (sum == sum);          // false if either endpoint dropped
        m[i] = ok ? 1.0f : 0.0f;
        w[i] = ok ? sum : 0.0f;
        if (ok) {
            touched[ss[i]] = 1;
            touched[dd[i]] = 1;
        }
    }
    mask_out[t] = make_float4(m[0], m[1], m[2], m[3]);
    w_out[t]    = make_float4(w[0], w[1], w[2], w[3]);
}

// ---------------------------------------------------------------------------
// Kernel D: node mask from touched bytes (4 nodes per thread)
// ---------------------------------------------------------------------------
__global__ __launch_bounds__(256) void nodemask_kernel(
    const uchar4* __restrict__ touched, float4* __restrict__ nm)
{
    const int t = blockIdx.x * blockDim.x + threadIdx.x;   // [0, NN/4)
    uchar4 tv = touched[t];
    nm[t] = make_float4(tv.x ? 1.f : 0.f, tv.y ? 1.f : 0.f,
                        tv.z ? 1.f : 0.f, tv.w ? 1.f : 0.f);
}

extern "C" void kernel_launch(void* const* d_in, const int* in_sizes, int n_in,
                              void* d_out, int out_size, void* d_ws, size_t ws_size,
                              hipStream_t stream)
{
    const float* h     = (const float*)d_in[0];
    const float* g     = (const float*)d_in[1];
    const int*   ei    = (const int*)d_in[2];
    const float* W1    = (const float*)d_in[3];
    const float* b1    = (const float*)d_in[4];
    const float* gamma = (const float*)d_in[5];
    const float* beta  = (const float*)d_in[6];
    const float* W2    = (const float*)d_in[7];
    const float* b2    = (const float*)d_in[8];

    float* out        = (float*)d_out;
    float* out_mask   = out;                       // [E]
    float* out_w      = out + (size_t)NE;          // [E]
    float* out_logits = out + 2 * (size_t)NE;      // [N]
    float* out_nm     = out_logits + (size_t)NN;   // [N]

    float*         kl      = (float*)d_ws;                           // N floats (1 MB)
    unsigned char* touched = (unsigned char*)((char*)d_ws + (size_t)NN * 4); // N bytes

    // W1P lives at the start of out_w: written by wpack, read by logits,
    // then fully overwritten by edge_kernel (in-stream order => safe).
    short* W1P = (short*)out_w;                    // 294912 B << NE*4

    hipLaunchKernelGGL(wpack_kernel, dim3(72), dim3(256), 0, stream, W1, W1P);
    hipLaunchKernelGGL(logits_kernel, dim3(NN / BM), dim3(256), 0, stream,
                       h, g, W1P, b1, gamma, beta, W2, b2, out_logits);
    hipLaunchKernelGGL(topk_kernel, dim3(NB), dim3(256), 0, stream,
                       out_logits, kl, touched);
    hipLaunchKernelGGL(edge_kernel, dim3(NE / 1024), dim3(256), 0, stream,
                       ei, kl, (float4*)out_mask, (float4*)out_w, touched);
    hipLaunchKernelGGL(nodemask_kernel, dim3(NN / 1024), dim3(256), 0, stream,
                       (const uchar4*)touched, (float4*)out_nm);
}

// Round 7
// 494.668 us; speedup vs baseline: 1.0534x; 1.0534x over previous
//
#include <hip/hip_runtime.h>
#include <math.h>

#define NPG 256
#define NB 1024
#define NN (NB * NPG)          // 262144 nodes
#define HID 192
#define HID2 384
#define NE 4194304
#define KTOP 231
#define LNEPS 1e-5f

#define BM 32                  // rows per block (logits kernel)

typedef short short8 __attribute__((ext_vector_type(8)));
typedef float f32x4  __attribute__((ext_vector_type(4)));

// fp32 -> bf16 (RNE) and back, bit-exact helpers
__device__ __forceinline__ short f2bf(float f) {
    unsigned u = __float_as_uint(f);
    u += 0x7fffu + ((u >> 16) & 1u);
    return (short)(u >> 16);
}
__device__ __forceinline__ float bf2f(short h) {
    return __uint_as_float(((unsigned)(unsigned short)h) << 16);
}

__device__ __forceinline__ void dec8(float4 a, float4 b, short8& hv, short8& lv) {
#define DEC1(i, val) { short h_ = f2bf(val); hv[i] = h_; lv[i] = f2bf((val) - bf2f(h_)); }
    DEC1(0, a.x) DEC1(1, a.y) DEC1(2, a.z) DEC1(3, a.w)
    DEC1(4, b.x) DEC1(5, b.y) DEC1(6, b.z) DEC1(7, b.w)
#undef DEC1
}

// ---------------------------------------------------------------------------
// Kernel W: pack W1 [192][384] fp32 into MFMA B-fragment order, bf16 hi/lo.
// Layout: [slice s:6][frag f:24][comp c:2][lane:64][e:8] halves.
// Fragment element: W1[s*32 + 8*(lane>>4) + e][f*16 + (lane&15)].
// ---------------------------------------------------------------------------
__global__ __launch_bounds__(256) void wpack_kernel(
    const float* __restrict__ W1, short* __restrict__ W1P)
{
    const int t    = blockIdx.x * 256 + threadIdx.x;   // 0..18431
    const int lane = t & 63;
    const int c    = (t >> 6) & 1;
    const int fs   = t >> 7;
    const int f    = fs % 24;
    const int s    = fs / 24;
    const int col  = f * 16 + (lane & 15);
    const int kb   = s * 32 + 8 * (lane >> 4);
    short8 o;
#define PK(e) { float w = W1[(size_t)(kb + e) * HID2 + col]; \
                short hi = f2bf(w); \
                o[e] = (c == 0) ? hi : f2bf(w - bf2f(hi)); }
    PK(0) PK(1) PK(2) PK(3) PK(4) PK(5) PK(6) PK(7)
#undef PK
    ((short8*)W1P)[t] = o;
}

// ---------------------------------------------------------------------------
// Kernel A: fused logits via bf16x3 emulated-fp32 MFMA GEMM (hh + hl + lh;
// ll term <= 2^-18 relative, dropped). Block = 32 rows x 384 cols, 4 waves
// each own 32 rows x 96 cols (2 M-frags x 6 N-frags of 16x16). K = 6x32.
// __launch_bounds__(256,4) caps total VGPR+AGPR at 128/wave so 4 waves/EU
// fit (prior rounds were silently AGPR-capped at 2 waves/EU: occupancy
// pinned at 22% across LDS 24-61KB and VGPR 88-128). B fragments are
// consumed per-n (live B regs 8-16, not 48) to fit the cap.
// ---------------------------------------------------------------------------
union SMemU {
    struct { short Xh[BM * HID]; short Xl[BM * HID]; } x;             // 24576 B
    struct { float2 red[BM][4]; float2 mrs[BM]; float pl[BM][4]; } e; // 1792 B
};

__global__ __launch_bounds__(256, 4) void logits_kernel(
    const float* __restrict__ h, const float* __restrict__ g,
    const short* __restrict__ W1P, const float* __restrict__ b1,
    const float* __restrict__ gamma, const float* __restrict__ beta,
    const float* __restrict__ W2, const float* __restrict__ b2,
    float* __restrict__ logits_out)
{
    __shared__ __align__(16) SMemU sm;

    const int tid   = threadIdx.x;
    const int lane  = tid & 63;
    const int wv    = tid >> 6;        // 0..3 : column quarter
    const int li    = lane & 15;
    const int gq    = lane >> 4;       // 0..3 : k-group
    const int row0  = blockIdx.x * BM;
    const int graph = row0 >> 8;

    // ---- stage X = h + g_rep, decomposed to bf16 hi/lo, swizzled ----
    {
        const float4* h4 = (const float4*)(h + (size_t)row0 * HID);
        const float4* g4 = (const float4*)(g + (size_t)graph * HID);
        #pragma unroll
        for (int it = 0; it < 3; ++it) {
            int fidx = tid + it * 256;           // 0..767
            int row  = fidx / 24;
            int k8   = fidx - row * 24;          // 8-elem group within row
            float4 a  = h4[row * 48 + k8 * 2];
            float4 b  = h4[row * 48 + k8 * 2 + 1];
            float4 ga = g4[k8 * 2];
            float4 gb = g4[k8 * 2 + 1];
            a.x += ga.x; a.y += ga.y; a.z += ga.z; a.w += ga.w;
            b.x += gb.x; b.y += gb.y; b.z += gb.z; b.w += gb.w;
            short8 hv, lv;
            dec8(a, b, hv, lv);
            int idx = row * HID + ((k8 ^ (row & 7)) << 3);   // 16B-granule swizzle
            *(short8*)(sm.x.Xh + idx) = hv;
            *(short8*)(sm.x.Xl + idx) = lv;
        }
    }
    __syncthreads();

    f32x4 acc[2][6];
    #pragma unroll
    for (int m = 0; m < 2; ++m)
        #pragma unroll
        for (int n = 0; n < 6; ++n)
            acc[m][n] = (f32x4){0.f, 0.f, 0.f, 0.f};

    const short8* wp = (const short8*)W1P;
    const int bbase = wv * 768 + lane;   // (wv*6 frags)*2 comp*64 lanes

    #pragma unroll
    for (int s = 0; s < 6; ++s) {
        // A fragments from swizzled LDS (16 VGPR live)
        short8 Ah[2], Al[2];
        #pragma unroll
        for (int m = 0; m < 2; ++m) {
            int row = m * 16 + li;
            int idx = row * HID + ((((s << 2) + gq) ^ (li & 7)) << 3);
            Ah[m] = *(const short8*)(sm.x.Xh + idx);
            Al[m] = *(const short8*)(sm.x.Xl + idx);
        }
        // B per-n: load one hi/lo fragment pair, use, release (8-16 regs live)
        #pragma unroll
        for (int n = 0; n < 6; ++n) {
            short8 Bh = wp[s * 3072 + bbase + n * 128];
            short8 Bl = wp[s * 3072 + bbase + n * 128 + 64];
            acc[0][n] = __builtin_amdgcn_mfma_f32_16x16x32_bf16(Ah[0], Bh, acc[0][n], 0, 0, 0);
            acc[0][n] = __builtin_amdgcn_mfma_f32_16x16x32_bf16(Ah[0], Bl, acc[0][n], 0, 0, 0);
            acc[0][n] = __builtin_amdgcn_mfma_f32_16x16x32_bf16(Al[0], Bh, acc[0][n], 0, 0, 0);
            acc[1][n] = __builtin_amdgcn_mfma_f32_16x16x32_bf16(Ah[1], Bh, acc[1][n], 0, 0, 0);
            acc[1][n] = __builtin_amdgcn_mfma_f32_16x16x32_bf16(Ah[1], Bl, acc[1][n], 0, 0, 0);
            acc[1][n] = __builtin_amdgcn_mfma_f32_16x16x32_bf16(Al[1], Bh, acc[1][n], 0, 0, 0);
        }
    }
    __syncthreads();   // Xh/Xl dead from here; epilogue scratch aliases them

    // ---- epilogue: +b1, LayerNorm, ReLU, dot W2 ----
    // C/D layout: col = n*16 + li (wave offset wv*96), row = m*16 + gq*4 + r
    float b1v[6], gav[6], bev[6], w2v[6];
    #pragma unroll
    for (int n = 0; n < 6; ++n) {
        int c = wv * 96 + n * 16 + li;
        b1v[n] = b1[c]; gav[n] = gamma[c]; bev[n] = beta[c]; w2v[n] = W2[c];
    }

    #pragma unroll
    for (int m = 0; m < 2; ++m) {
        #pragma unroll
        for (int r = 0; r < 4; ++r) {
            float s1 = 0.f, s2 = 0.f;
            #pragma unroll
            for (int n = 0; n < 6; ++n) {
                float z = acc[m][n][r] + b1v[n];
                s1 += z;
                s2 = fmaf(z, z, s2);
            }
            #pragma unroll
            for (int off = 1; off < 16; off <<= 1) {
                s1 += __shfl_xor(s1, off);
                s2 += __shfl_xor(s2, off);
            }
            if (li == 0) {
                int row = m * 16 + gq * 4 + r;
                sm.e.red[row][wv] = make_float2(s1, s2);
            }
        }
    }
    __syncthreads();
    if (tid < BM) {
        float2 p0 = sm.e.red[tid][0], p1 = sm.e.red[tid][1];
        float2 p2 = sm.e.red[tid][2], p3 = sm.e.red[tid][3];
        float s1 = (p0.x + p1.x) + (p2.x + p3.x);
        float s2 = (p0.y + p1.y) + (p2.y + p3.y);
        float mu  = s1 * (1.f / HID2);
        float var = s2 * (1.f / HID2) - mu * mu;
        sm.e.mrs[tid] = make_float2(mu, rsqrtf(var + LNEPS));
    }
    __syncthreads();

    #pragma unroll
    for (int m = 0; m < 2; ++m) {
        #pragma unroll
        for (int r = 0; r < 4; ++r) {
            int row = m * 16 + gq * 4 + r;
            float2 v = sm.e.mrs[row];
            float p = 0.f;
            #pragma unroll
            for (int n = 0; n < 6; ++n) {
                float z  = acc[m][n][r] + b1v[n];
                float zn = (z - v.x) * v.y * gav[n] + bev[n];
                p = fmaf(fmaxf(zn, 0.f), w2v[n], p);
            }
            #pragma unroll
            for (int off = 1; off < 16; off <<= 1) p += __shfl_xor(p, off);
            if (li == 0) sm.e.pl[row][wv] = p;
        }
    }
    __syncthreads();
    if (tid < BM) {
        float lg = (sm.e.pl[tid][0] + sm.e.pl[tid][1]) + (sm.e.pl[tid][2] + sm.e.pl[tid][3]);
        logits_out[row0 + tid] = lg + b2[0];
    }
}

// ---------------------------------------------------------------------------
// Kernel B: per-graph top-K via rank counting (stable, ties by lower index =
// jax.lax.top_k). Emits kl[n] = kept ? logit : NaN (single 4B gather later).
// Also zeroes touched bytes.
// ---------------------------------------------------------------------------
__global__ __launch_bounds__(256) void topk_kernel(
    const float* __restrict__ logits, float* __restrict__ kl,
    unsigned char* __restrict__ touched)
{
    __shared__ float arr[NPG];
    const int tid = threadIdx.x;
    const int n = blockIdx.x * NPG + tid;
    float v = logits[n];
    arr[tid] = v;
    touched[n] = 0;
    __syncthreads();
    int rank = 0;
    #pragma unroll 16
    for (int j = 0; j < NPG; ++j) {
        float a = arr[j];
        rank += (a > v || (a == v && j < tid)) ? 1 : 0;
    }
    kl[n] = (rank < KTOP) ? v : __builtin_nanf("");
}

// ---------------------------------------------------------------------------
// Kernel C: edge mask + weight + touched marking. NaN-poisoned logits make
// mask = !isnan(ls+ld). Plain idempotent uchar stores to touched.
// ---------------------------------------------------------------------------
__global__ __launch_bounds__(256) void edge_kernel(
    const int* __restrict__ ei, const float* __restrict__ kl,
    float4* __restrict__ mask_out, float4* __restrict__ w_out,
    unsigned char* __restrict__ touched)
{
    const int t = blockIdx.x * blockDim.x + threadIdx.x;   // [0, NE/4)
    const int4 s4 = ((const int4*)ei)[t];
    const int4 d4 = ((const int4*)(ei + NE))[t];

    float m[4], w[4];
    const int ss[4] = {s4.x, s4.y, s4.z, s4.w};
    const int dd[4] = {d4.x, d4.y, d4.z, d4.w};
    #pragma unroll
    for (int i = 0; i < 4; ++i) {
        float ls = kl[ss[i]];
        float ld = kl[dd[i]];
        float sum = ls + ld;
        bool ok = (sum == sum);          // false if either endpoint dropped
        m[i] = ok ? 1.0f : 0.0f;
        w[i] = ok ? sum : 0.0f;
        if (ok) {
            touched[ss[i]] = 1;
            touched[dd[i]] = 1;
        }
    }
    mask_out[t] = make_float4(m[0], m[1], m[2], m[3]);
    w_out[t]    = make_float4(w[0], w[1], w[2], w[3]);
}

// ---------------------------------------------------------------------------
// Kernel D: node mask from touched bytes (4 nodes per thread)
// ---------------------------------------------------------------------------
__global__ __launch_bounds__(256) void nodemask_kernel(
    const uchar4* __restrict__ touched, float4* __restrict__ nm)
{
    const int t = blockIdx.x * blockDim.x + threadIdx.x;   // [0, NN/4)
    uchar4 tv = touched[t];
    nm[t] = make_float4(tv.x ? 1.f : 0.f, tv.y ? 1.f : 0.f,
                        tv.z ? 1.f : 0.f, tv.w ? 1.f : 0.f);
}

extern "C" void kernel_launch(void* const* d_in, const int* in_sizes, int n_in,
                              void* d_out, int out_size, void* d_ws, size_t ws_size,
                              hipStream_t stream)
{
    const float* h     = (const float*)d_in[0];
    const float* g     = (const float*)d_in[1];
    const int*   ei    = (const int*)d_in[2];
    const float* W1    = (const float*)d_in[3];
    const float* b1    = (const float*)d_in[4];
    const float* gamma = (const float*)d_in[5];
    const float* beta  = (const float*)d_in[6];
    const float* W2    = (const float*)d_in[7];
    const float* b2    = (const float*)d_in[8];

    float* out        = (float*)d_out;
    float* out_mask   = out;                       // [E]
    float* out_w      = out + (size_t)NE;          // [E]
    float* out_logits = out + 2 * (size_t)NE;      // [N]
    float* out_nm     = out_logits + (size_t)NN;   // [N]

    float*         kl      = (float*)d_ws;                           // N floats (1 MB)
    unsigned char* touched = (unsigned char*)((char*)d_ws + (size_t)NN * 4); // N bytes

    // W1P lives at the start of out_w: written by wpack, read by logits,
    // then fully overwritten by edge_kernel (in-stream order => safe).
    short* W1P = (short*)out_w;                    // 294912 B << NE*4

    hipLaunchKernelGGL(wpack_kernel, dim3(72), dim3(256), 0, stream, W1, W1P);
    hipLaunchKernelGGL(logits_kernel, dim3(NN / BM), dim3(256), 0, stream,
                       h, g, W1P, b1, gamma, beta, W2, b2, out_logits);
    hipLaunchKernelGGL(topk_kernel, dim3(NB), dim3(256), 0, stream,
                       out_logits, kl, touched);
    hipLaunchKernelGGL(edge_kernel, dim3(NE / 1024), dim3(256), 0, stream,
                       ei, kl, (float4*)out_mask, (float4*)out_w, touched);
    hipLaunchKernelGGL(nodemask_kernel, dim3(NN / 1024), dim3(256), 0, stream,
                       (const uchar4*)touched, (float4*)out_nm);
}